// Round 8
// baseline (121.081 us; speedup 1.0000x reference)
//
#include <hip/hip_runtime.h>
#include <hip/hip_bf16.h>

// MaskedSelfAttention: B=2, S=2048, D=1024, H=16, depth=64.
// prep (convert+transpose+ctr-zero) -> fused QKV GEMM -> flash attn
// (anti-causal: valid k>q; q=2047 row = mean(V) via vmean) -> combine ->
// out GEMM.
// R8: attn work-stealing — 512 persistent blocks (2/CU) dynamically pull
// the 768 R7 work units (heavy-first order) from a global atomic counter.
// Balance no longer depends on undefined workgroup->CU assignment.

using bf16   = __bf16;
using bf16x2 = __attribute__((ext_vector_type(2))) __bf16;
using bf16x4 = __attribute__((ext_vector_type(4))) __bf16;
using bf16x8 = __attribute__((ext_vector_type(8))) __bf16;
using f32x4  = __attribute__((ext_vector_type(4))) float;
using uintx2 = __attribute__((ext_vector_type(2))) unsigned int;
using uintx4 = __attribute__((ext_vector_type(4))) unsigned int;

// unit table sorted heavy-first: jq | kbeg<<8 | kend<<16 | mode<<24
// (mode 0: whole tile, normalized write; 1: first k-chunk partial -> aop;
//  2: second k-chunk partial -> o2buf)
__device__ const unsigned int kUnitTab[24] = {
    0u | (0u << 8)  | (16u << 16) | (1u << 24),   // 16
    0u | (16u << 8) | (32u << 16) | (2u << 24),   // 16
    8u | (16u << 8) | (32u << 16) | (0u << 24),   // 16
    1u | (2u << 8)  | (17u << 16) | (1u << 24),   // 15
    1u | (17u << 8) | (32u << 16) | (2u << 24),   // 15
    2u | (4u << 8)  | (18u << 16) | (1u << 24),   // 14
    2u | (18u << 8) | (32u << 16) | (2u << 24),   // 14
    9u | (18u << 8) | (32u << 16) | (0u << 24),   // 14
    3u | (6u << 8)  | (19u << 16) | (1u << 24),   // 13
    3u | (19u << 8) | (32u << 16) | (2u << 24),   // 13
    4u | (8u << 8)  | (20u << 16) | (1u << 24),   // 12
    4u | (20u << 8) | (32u << 16) | (2u << 24),   // 12
    10u | (20u << 8) | (32u << 16) | (0u << 24),  // 12
    5u | (10u << 8) | (21u << 16) | (1u << 24),   // 11
    5u | (21u << 8) | (32u << 16) | (2u << 24),   // 11
    6u | (12u << 8) | (22u << 16) | (1u << 24),   // 10
    6u | (22u << 8) | (32u << 16) | (2u << 24),   // 10
    11u | (22u << 8) | (32u << 16) | (0u << 24),  // 10
    7u | (14u << 8) | (23u << 16) | (1u << 24),   // 9
    7u | (23u << 8) | (32u << 16) | (2u << 24),   // 9
    12u | (24u << 8) | (32u << 16) | (0u << 24),  // 8
    13u | (26u << 8) | (32u << 16) | (0u << 24),  // 6
    14u | (28u << 8) | (32u << 16) | (0u << 24),  // 4
    15u | (30u << 8) | (32u << 16) | (0u << 24)}; // 2

__device__ __forceinline__ void load_lds16(const void* g, void* l) {
  __builtin_amdgcn_global_load_lds(
      (const __attribute__((address_space(1))) void*)g,
      (__attribute__((address_space(3))) void*)l, 16, 0, 0);
}

__device__ __forceinline__ unsigned int packbf(float a, float b) {
  bf16x2 v;
  v[0] = (bf16)a;
  v[1] = (bf16)b;
  return __builtin_bit_cast(unsigned int, v);
}

// Redistribute packed P words across hi-groups (in-register P, R4).
__device__ __forceinline__ void xchg_p(unsigned int u, unsigned int v, int hi,
                                       unsigned int& f, unsigned int& s) {
#if __has_builtin(__builtin_amdgcn_permlane32_swap) && \
    __has_builtin(__builtin_amdgcn_permlane16_swap)
  uintx2 ab = __builtin_amdgcn_permlane32_swap(u, v, false, false);
  uintx2 fs = __builtin_amdgcn_permlane16_swap(ab[0], ab[1], false, false);
  f = fs[0];
  s = fs[1];
#else
  unsigned int a = (hi < 2) ? u : (unsigned int)__shfl_xor((int)v, 32);
  unsigned int b = (hi < 2) ? (unsigned int)__shfl_xor((int)u, 32) : v;
  unsigned int a16 = (unsigned int)__shfl_xor((int)a, 16);
  unsigned int b16 = (unsigned int)__shfl_xor((int)b, 16);
  f = (hi & 1) ? b16 : a;
  s = (hi & 1) ? b : a16;
#endif
}

// ---------------- prep: convert x + transpose 4 weights + zero ctr --------
__global__ __launch_bounds__(256) void prep_kernel(
    const float* __restrict__ x, bf16* __restrict__ xb,
    const float* __restrict__ wq, const float* __restrict__ wk,
    const float* __restrict__ wv, const float* __restrict__ wo,
    bf16* __restrict__ wT, int* __restrict__ ctr) {
  const int t = threadIdx.x;
  int bid = blockIdx.x;
  if (bid == 0 && t == 0) *ctr = 0;  // work-steal queue head (stream-ordered)
  if (bid < 4096) {  // convert x: f32 -> bf16
    const int i = (bid * 256 + t) * 4;
    const float4 v = *(const float4*)(x + i);
    bf16x4 o;
    o[0] = (bf16)v.x; o[1] = (bf16)v.y; o[2] = (bf16)v.z; o[3] = (bf16)v.w;
    *(bf16x4*)(xb + i) = o;
    return;
  }
  bid -= 4096;
  const int sel = bid >> 8;  // 0..3 : wq wk wv wo
  const float* w = (sel == 0) ? wq : (sel == 1) ? wk : (sel == 2) ? wv : wo;
  bf16* out = wT + (size_t)sel * 1048576;
  __shared__ float tile[64][65];
  const int n0 = (bid & 15) * 64;
  const int k0 = ((bid >> 4) & 15) * 64;
#pragma unroll
  for (int p = 0; p < 4; ++p) {
    const int row = p * 16 + (t >> 4);
    const int c4  = (t & 15) * 4;
    const float4 v = *(const float4*)&w[(size_t)(k0 + row) * 1024 + n0 + c4];
    tile[row][c4 + 0] = v.x; tile[row][c4 + 1] = v.y;
    tile[row][c4 + 2] = v.z; tile[row][c4 + 3] = v.w;
  }
  __syncthreads();
#pragma unroll
  for (int p = 0; p < 4; ++p) {
    const int rn = p * 16 + (t >> 4);
    const int c4 = (t & 15) * 4;
    bf16x4 o;
#pragma unroll
    for (int j = 0; j < 4; ++j) o[j] = (bf16)tile[c4 + j][rn];
    *(bf16x4*)&out[(size_t)(n0 + rn) * 1024 + k0 + c4] = o;
  }
}

// ---------------- GEMM C = A[M][1024] * Bt[N][1024]^T ----------------
template <int MODE>
__global__ __launch_bounds__(256, 2) void gemm_bt(
    const bf16* __restrict__ A, const bf16* __restrict__ Bt,
    const float* __restrict__ bias0, const float* __restrict__ bias1,
    const float* __restrict__ bias2, bf16* __restrict__ qf,
    bf16* __restrict__ kf, bf16* __restrict__ vt, float* __restrict__ fout,
    int Nblocks) {
  __shared__ __align__(16) char smem[32768];
  char* sA = smem;
  char* sB = smem + 16384;
  const int tid = threadIdx.x;
  const int lane = tid & 63;
  const int w = tid >> 6;
  const int wm = w >> 1, wn = w & 1;
  const int bid = blockIdx.x;
  const int m0 = (bid / Nblocks) * 128;
  const int n0 = (bid % Nblocks) * 128;

  const char* Ab = (const char*)A;
  const char* Bb = (const char*)Bt;
  size_t srcA[4], srcB[4];
#pragma unroll
  for (int it = 0; it < 4; ++it) {
    const int o = it * 4096 + tid * 16;
    const int r = o >> 7;
    const int cg = ((o >> 4) & 7) ^ (r & 7);
    srcA[it] = (size_t)(m0 + r) * 2048 + cg * 16;
    srcB[it] = (size_t)(n0 + r) * 2048 + cg * 16;
  }

  f32x4 acc[4][4] = {};

  for (int kt = 0; kt < 16; ++kt) {
    const size_t kb = (size_t)kt * 128;
#pragma unroll
    for (int it = 0; it < 4; ++it) {
      load_lds16(Ab + srcA[it] + kb, sA + it * 4096 + w * 1024);
      load_lds16(Bb + srcB[it] + kb, sB + it * 4096 + w * 1024);
    }
    asm volatile("s_waitcnt vmcnt(0)" ::: "memory");
    __syncthreads();
#pragma unroll
    for (int ks = 0; ks < 2; ++ks) {
      bf16x8 aF[4], bF[4];
      const int g = (lane >> 4) + 4 * ks;
#pragma unroll
      for (int i = 0; i < 4; ++i) {
        const int ra = wm * 64 + i * 16 + (lane & 15);
        aF[i] = *(const bf16x8*)(sA + ra * 128 + ((g ^ (ra & 7)) << 4));
        const int rb = wn * 64 + i * 16 + (lane & 15);
        bF[i] = *(const bf16x8*)(sB + rb * 128 + ((g ^ (rb & 7)) << 4));
      }
#pragma unroll
      for (int mi = 0; mi < 4; ++mi)
#pragma unroll
        for (int ni = 0; ni < 4; ++ni)
          acc[mi][ni] = __builtin_amdgcn_mfma_f32_16x16x32_bf16(
              aF[mi], bF[ni], acc[mi][ni], 0, 0, 0);
    }
    __syncthreads();
  }

  const int cn = lane & 15;
  const int gq = lane >> 4;
#pragma unroll
  for (int mi = 0; mi < 4; ++mi) {
#pragma unroll
    for (int ni = 0; ni < 4; ++ni) {
      const int n  = n0 + wn * 64 + ni * 16 + cn;
      const int mb = m0 + wm * 64 + mi * 16 + 4 * gq;
      const f32x4 v = acc[mi][ni];
      if (MODE == 0) {
        const float bias =
            (n < 1024) ? bias0[n] : ((n < 2048) ? bias1[n - 1024] : bias2[n - 2048]);
        if (n < 2048) {
          bf16* dst = (n < 1024) ? qf : kf;
          const int nn = n & 1023;
#pragma unroll
          for (int j = 0; j < 4; ++j)
            dst[(size_t)(mb + j) * 1024 + nn] = (bf16)(v[j] + bias);
        } else {
          const int nn = n - 2048;
          const int hh = nn >> 6, dd = nn & 63;
          const int bb = mb >> 11, ss = mb & 2047;
          bf16x4 pk;
#pragma unroll
          for (int j = 0; j < 4; ++j) pk[j] = (bf16)(v[j] + bias);
          *(bf16x4*)(vt + ((size_t)((bb * 16 + hh) * 64 + dd) * 2048 + ss)) = pk;
        }
      } else {
        const float bias = bias0[n];
#pragma unroll
        for (int j = 0; j < 4; ++j)
          fout[(size_t)(mb + j) * 1024 + n] = v[j] + bias;
      }
    }
  }
}

// ---------------- flash attention v8 (valid keys: k > q) ----------------
// 512 persistent blocks (2/CU) steal units 0..767 from a global counter.
// Unit g: type = g>>5 (kUnitTab, heavy-first), bh = g&31. Unit body
// identical to R7: 4 waves x 32 q-rows, in-register P, 2-buffer staging,
// flash partials for split tiles.
__global__ __launch_bounds__(256, 2) void attn_kernel(
    const bf16* __restrict__ qf, const bf16* __restrict__ kf,
    const bf16* __restrict__ vt, bf16* __restrict__ ao,
    bf16* __restrict__ o2buf, float* __restrict__ mlbuf,
    int* __restrict__ ctr) {
  __shared__ __align__(16) char smem[32768];  // sK[2][8192] | sV[2][8192]
  __shared__ int s_g;

  const int tid  = threadIdx.x;
  const int lane = tid & 63;
  const int hi   = lane >> 4;
  const int qlo  = lane & 15;
  const int w    = tid >> 6;

  const int sr  = tid >> 3;              // staging row 0..31 (pass 2: +32)
  const int scg = (tid & 7) ^ (sr & 7);  // pre-swizzled source chunk

  bf16x8 onesB;
#pragma unroll
  for (int i = 0; i < 8; ++i) onesB[i] = (bf16)1.0f;

  for (;;) {
    if (tid == 0) s_g = atomicAdd(ctr, 1);
    __syncthreads();
    const int g = s_g;
    if (g >= 768) break;  // g is block-uniform -> convergent exit

    const unsigned int ent = kUnitTab[g >> 5];
    const int bh = g & 31;
    const int b = bh >> 4, h = bh & 15;
    const int jq = ent & 255, kbeg = (ent >> 8) & 255,
              kend = (ent >> 16) & 255;
    const int mode = ent >> 24;

    const char* kbase = (const char*)kf + ((size_t)b * 2048) * 2048 + h * 128;
    const char* vbase = (const char*)vt + (size_t)bh * 262144;
    const char* qbb   = (const char*)qf + ((size_t)b * 2048) * 2048 + h * 128;

    const int q0 = jq * 128;
    const int qb = q0 + w * 32;

    // Q fragments for 2 column-tiles (pre-scaled by 1/8 -- exact in bf16)
    bf16x8 qA[2][2];
#pragma unroll
    for (int nt = 0; nt < 2; ++nt) {
      const char* qrow = qbb + (size_t)(qb + 16 * nt + qlo) * 2048;
#pragma unroll
      for (int ks = 0; ks < 2; ++ks) {
        qA[nt][ks] = *(const bf16x8*)(qrow + ks * 64 + hi * 16);
#pragma unroll
        for (int i = 0; i < 8; ++i)
          qA[nt][ks][i] = (bf16)(0.125f * (float)qA[nt][ks][i]);
      }
    }

    float m[2] = {-1e30f, -1e30f};
    f32x4 lacc[2] = {};
    f32x4 O[2][4] = {};

    // stage absolute k-tile kt into buffer bufi
    auto STAGE = [&](int kt, int bufi) {
      char* dK = smem + bufi * 8192 + w * 1024;
      char* dV = smem + 16384 + bufi * 8192 + w * 1024;
      const int kn = kt * 64;
#pragma unroll
      for (int p = 0; p < 2; ++p) {
        load_lds16(kbase + (size_t)(kn + sr + 32 * p) * 2048 + scg * 16,
                   dK + p * 4096);
        load_lds16(vbase + (size_t)(sr + 32 * p) * 4096 + (size_t)kn * 2 +
                       scg * 16,
                   dV + p * 4096);
      }
    };

    STAGE(kbeg, 0);
    __syncthreads();

    for (int kt = kbeg; kt < kend; ++kt) {
      const int cur = (kt - kbeg) & 1;

      // issue next-tile staging (drains at this iteration's closing barrier)
      if (kt + 1 < kend) STAGE(kt + 1, cur ^ 1);

      const char* bK = smem + cur * 8192;
      const char* bV = smem + 16384 + cur * 8192;

      // QK^T swapped: sc[nt][t] rows = k (16t+4hi+j), col = q (16nt+qlo);
      // kF shared across both nt tiles.
      f32x4 sc[2][4] = {};
#pragma unroll
      for (int ks = 0; ks < 2; ++ks) {
        const int gg = hi + 4 * ks;
#pragma unroll
        for (int t = 0; t < 4; ++t) {
          const int rk = t * 16 + qlo;
          const bf16x8 kF =
              *(const bf16x8*)(bK + rk * 128 + ((gg ^ (rk & 7)) << 4));
          sc[0][t] = __builtin_amdgcn_mfma_f32_16x16x32_bf16(kF, qA[0][ks],
                                                             sc[0][t], 0, 0, 0);
          sc[1][t] = __builtin_amdgcn_mfma_f32_16x16x32_bf16(kF, qA[1][ks],
                                                             sc[1][t], 0, 0, 0);
        }
      }

      if (kt * 64 < q0 + 128) {  // tiles overlapping the q-range: mask k <= q
        const int k0t = kt * 64;
#pragma unroll
        for (int nt = 0; nt < 2; ++nt)
#pragma unroll
          for (int t = 0; t < 4; ++t)
#pragma unroll
            for (int j = 0; j < 4; ++j) {
              const int kk = k0t + t * 16 + 4 * hi + j;
              const int qq = qb + 16 * nt + qlo;
              if (kk <= qq) sc[nt][t][j] = -1e30f;
            }
      }

      // per-q tile max (lane-local 16 vals + 2 shfl)
      float tm[2];
#pragma unroll
      for (int nt = 0; nt < 2; ++nt) {
        float v = sc[nt][0][0];
#pragma unroll
        for (int t = 0; t < 4; ++t)
#pragma unroll
          for (int j = 0; j < 4; ++j) v = fmaxf(v, sc[nt][t][j]);
        v = fmaxf(v, __shfl_xor(v, 16));
        v = fmaxf(v, __shfl_xor(v, 32));
        tm[nt] = v;
      }

      // T13 defer-max: rescale only when some row's max grew by > 8
      const bool grew = (tm[0] - m[0] > 8.0f) || (tm[1] - m[1] > 8.0f);
      if (__any(grew)) {
#pragma unroll
        for (int nt = 0; nt < 2; ++nt) {
          const float mn = fmaxf(m[nt], tm[nt]);
          const float al = __expf(m[nt] - mn);
          m[nt] = mn;
#pragma unroll
          for (int j = 0; j < 4; ++j) {
            const float alj = __shfl(al, 4 * hi + j);
            lacc[nt][j] *= alj;
#pragma unroll
            for (int dt = 0; dt < 4; ++dt) O[nt][dt][j] *= alj;
          }
        }
      }

      // P = exp(s - m) packed to bf16 pairs, redistributed in-register to
      // the PV A-fragment layout (no LDS round-trip).
      bf16x8 pA[2][2];
#pragma unroll
      for (int nt = 0; nt < 2; ++nt) {
        unsigned int W[4][2];
#pragma unroll
        for (int t = 0; t < 4; ++t)
#pragma unroll
          for (int p = 0; p < 2; ++p)
            W[t][p] = packbf(__expf(sc[nt][t][2 * p] - m[nt]),
                             __expf(sc[nt][t][2 * p + 1] - m[nt]));
#pragma unroll
        for (int ks = 0; ks < 2; ++ks) {
          uintx4 w4;
#pragma unroll
          for (int p = 0; p < 2; ++p) {
            unsigned int f, s;
            xchg_p(W[2 * ks][p], W[2 * ks + 1][p], hi, f, s);
            w4[p] = f;
            w4[2 + p] = s;
          }
          pA[nt][ks] = __builtin_bit_cast(bf16x8, w4);
          lacc[nt] = __builtin_amdgcn_mfma_f32_16x16x32_bf16(pA[nt][ks], onesB,
                                                             lacc[nt], 0, 0, 0);
        }
      }

      // PV: O[q][d] += P*V ; vF shared across both nt tiles
#pragma unroll
      for (int ks = 0; ks < 2; ++ks) {
        const int gg = hi + 4 * ks;
#pragma unroll
        for (int dt = 0; dt < 4; ++dt) {
          const int rv = dt * 16 + qlo;
          const bf16x8 vF =
              *(const bf16x8*)(bV + rv * 128 + ((gg ^ (rv & 7)) << 4));
          O[0][dt] = __builtin_amdgcn_mfma_f32_16x16x32_bf16(pA[0][ks], vF,
                                                             O[0][dt], 0, 0, 0);
          O[1][dt] = __builtin_amdgcn_mfma_f32_16x16x32_bf16(pA[1][ks], vF,
                                                             O[1][dt], 0, 0, 0);
        }
      }
      __syncthreads();
    }

    if (mode == 0) {
      // normalized write (O rows 4*hi+j; lacc[j] same rows -> lane-local)
#pragma unroll
      for (int nt = 0; nt < 2; ++nt)
#pragma unroll
        for (int j = 0; j < 4; ++j) {
          const float linv = (lacc[nt][j] > 0.f) ? 1.f / lacc[nt][j] : 0.f;
          const int qg = qb + 16 * nt + 4 * hi + j;
#pragma unroll
          for (int dt = 0; dt < 4; ++dt)
            ao[(size_t)(b * 2048 + qg) * 1024 + h * 64 + dt * 16 + qlo] =
                (bf16)(O[nt][dt][j] * linv);
        }
    } else {
      // flash partial write: unnormalized O (bf16) + m,l (f32)
      const int qtbh = jq * 32 + bh;
      const int slot = mode - 1;
#pragma unroll
      for (int nt = 0; nt < 2; ++nt)
#pragma unroll
        for (int j = 0; j < 4; ++j) {
          const int r = w * 32 + 16 * nt + 4 * hi + j;  // row within q-tile
#pragma unroll
          for (int dt = 0; dt < 4; ++dt) {
            const bf16 vv = (bf16)O[nt][dt][j];
            if (mode == 1)
              ao[(size_t)(b * 2048 + q0 + r) * 1024 + h * 64 + dt * 16 + qlo] =
                  vv;
            else
              o2buf[(size_t)(qtbh * 128 + r) * 64 + dt * 16 + qlo] = vv;
          }
        }
      if (qlo == 0) {
#pragma unroll
        for (int nt = 0; nt < 2; ++nt)
#pragma unroll
          for (int j = 0; j < 4; ++j)
            mlbuf[((qtbh * 2 + slot) * 2 + 1) * 128 +
                  (w * 32 + 16 * nt + 4 * hi + j)] = lacc[nt][j];
      }
      if (hi == 0) {
#pragma unroll
        for (int nt = 0; nt < 2; ++nt)
          mlbuf[((qtbh * 2 + slot) * 2 + 0) * 128 + (w * 32 + 16 * nt + qlo)] =
              m[nt];
      }
    }
  }
}

// ---------------- combine: merge the two k-chunk partials (jq=0..7) -------
__global__ __launch_bounds__(256) void combine_kernel(
    const bf16* __restrict__ o2buf, const float* __restrict__ mlbuf,
    bf16* __restrict__ ao) {
  const int qtbh = blockIdx.x;  // jq*32 + bh, jq in 0..7
  const int jq = qtbh >> 5, bh = qtbh & 31;
  const int b = bh >> 4, h = bh & 15;
  const int t = threadIdx.x;
  const int r = t >> 1;
  const int c0 = (t & 1) * 32;

  const float m1 = mlbuf[((qtbh * 2 + 0) * 2 + 0) * 128 + r];
  const float l1 = mlbuf[((qtbh * 2 + 0) * 2 + 1) * 128 + r];
  const float m2 = mlbuf[((qtbh * 2 + 1) * 2 + 0) * 128 + r];
  const float l2 = mlbuf[((qtbh * 2 + 1) * 2 + 1) * 128 + r];
  const float M  = fmaxf(m1, m2);
  const float w1 = __expf(m1 - M), w2 = __expf(m2 - M);
  const float denom = w1 * l1 + w2 * l2;
  const float linv = (denom > 0.f) ? 1.f / denom : 0.f;

  bf16* arow = ao + ((size_t)(b * 2048 + jq * 128 + r) * 1024 + h * 64 + c0);
  const bf16* o2row = o2buf + ((size_t)(qtbh * 128 + r) * 64 + c0);
#pragma unroll
  for (int i = 0; i < 4; ++i) {
    const bf16x8 o1 = *(const bf16x8*)(arow + i * 8);
    const bf16x8 o2 = *(const bf16x8*)(o2row + i * 8);
    bf16x8 o;
#pragma unroll
    for (int j = 0; j < 8; ++j)
      o[j] = (bf16)((w1 * (float)o1[j] + w2 * (float)o2[j]) * linv);
    *(bf16x8*)(arow + i * 8) = o;
  }
}

// ---------------- last-row fix: ao[q=2047] = mean over s of V ----------------
__global__ __launch_bounds__(256) void vmean_kernel(const bf16* __restrict__ vt,
                                                    bf16* __restrict__ ao) {
  const int tid = threadIdx.x;
  const int lane = tid & 63, w = tid >> 6;
  const int gw = blockIdx.x * 4 + w;  // 0..2047 == bh*64 + d
  const int bh = gw >> 6, d = gw & 63;
  const int b = bh >> 4, h = bh & 15;
  const bf16x8* p = (const bf16x8*)(vt + (size_t)gw * 2048 + lane * 32);
  float s = 0.f;
#pragma unroll
  for (int i = 0; i < 4; ++i) {
    const bf16x8 v = p[i];
#pragma unroll
    for (int j = 0; j < 8; ++j) s += (float)v[j];
  }
  for (int off = 1; off < 64; off <<= 1) s += __shfl_xor(s, off);
  if (lane == 0)
    ao[(size_t)(b * 2048 + 2047) * 1024 + h * 64 + d] = (bf16)(s * (1.f / 2048.f));
}

extern "C" void kernel_launch(void* const* d_in, const int* in_sizes, int n_in,
                              void* d_out, int out_size, void* d_ws,
                              size_t ws_size, hipStream_t stream) {
  const float* x  = (const float*)d_in[0];
  const float* wq = (const float*)d_in[2];
  const float* bq = (const float*)d_in[3];
  const float* wk = (const float*)d_in[4];
  const float* bk = (const float*)d_in[5];
  const float* wv = (const float*)d_in[6];
  const float* bv = (const float*)d_in[7];
  const float* wo = (const float*)d_in[8];
  const float* bo = (const float*)d_in[9];
  float* out = (float*)d_out;

  // 50.33 MB of bf16 tensors + trailing work-steal counter
  if (ws_size < (size_t)25165824 * 2 + 64) return;

  bf16* ws    = (bf16*)d_ws;
  bf16* xb    = ws;                     // [4096][1024]; reused as partials
  bf16* wqkvT = xb + 4194304;           // [3072][1024]
  bf16* woT   = wqkvT + 3145728;        // [1024][1024]
  bf16* qfp   = woT + 1048576;          // [4096][1024] flat
  bf16* kfp   = qfp + 4194304;          // [4096][1024] flat
  bf16* vtp   = kfp + 4194304;          // [b][h][d][s]
  bf16* aop   = vtp + 4194304;          // [4096][1024] flat
  int*  ctr   = (int*)(aop + 4194304);  // work-steal queue head

  // partial scratch (xb is dead after the QKV GEMM):
  bf16*  o2buf = xb;                         // 8qt*32bh*128*64 bf16 = 4 MiB
  float* mlbuf = (float*)(xb + 2097152);     // 8*32*2*2*128 f32 = 512 KiB

  prep_kernel<<<5120, 256, 0, stream>>>(x, xb, wq, wk, wv, wo, wqkvT, ctr);

  gemm_bt<0><<<32 * 24, 256, 0, stream>>>(xb, wqkvT, bq, bk, bv, qfp, kfp, vtp,
                                          nullptr, 24);
  attn_kernel<<<512, 256, 0, stream>>>(qfp, kfp, vtp, aop, o2buf, mlbuf, ctr);
  vmean_kernel<<<512, 256, 0, stream>>>(vtp, aop);
  combine_kernel<<<256, 256, 0, stream>>>(o2buf, mlbuf, aop);
  gemm_bt<1><<<32 * 8, 256, 0, stream>>>(aop, woT, bo, nullptr, nullptr, nullptr,
                                         nullptr, nullptr, out, 8);
}

// Round 9
// 108.011 us; speedup vs baseline: 1.1210x; 1.1210x over previous
//
#include <hip/hip_runtime.h>
#include <hip/hip_bf16.h>

// MaskedSelfAttention: B=2, S=2048, D=1024, H=16, depth=64.
// prep (convert+transpose) -> fused QKV GEMM -> flash attn (anti-causal:
// valid k>q; q=2047 row = mean(V) via vmean) -> combine -> out GEMM.
// R9: attn uniform static units — 512 blocks = 16 units x 32 bh, EVERY
// block does exactly 17 k-tile-iters (heavy q-tiles split 17/(15-2j),
// light tiles chained after remainders). bh in low blockIdx bits keeps
// same-head blocks on one XCD (R8 lesson: FETCH 12->58 MB without it).

using bf16   = __bf16;
using bf16x2 = __attribute__((ext_vector_type(2))) __bf16;
using bf16x4 = __attribute__((ext_vector_type(4))) __bf16;
using bf16x8 = __attribute__((ext_vector_type(8))) __bf16;
using f32x4  = __attribute__((ext_vector_type(4))) float;
using uintx2 = __attribute__((ext_vector_type(2))) unsigned int;
using uintx4 = __attribute__((ext_vector_type(4))) unsigned int;

__device__ __forceinline__ void load_lds16(const void* g, void* l) {
  __builtin_amdgcn_global_load_lds(
      (const __attribute__((address_space(1))) void*)g,
      (__attribute__((address_space(3))) void*)l, 16, 0, 0);
}

__device__ __forceinline__ unsigned int packbf(float a, float b) {
  bf16x2 v;
  v[0] = (bf16)a;
  v[1] = (bf16)b;
  return __builtin_bit_cast(unsigned int, v);
}

// Redistribute packed P words across hi-groups (in-register P, R4).
__device__ __forceinline__ void xchg_p(unsigned int u, unsigned int v, int hi,
                                       unsigned int& f, unsigned int& s) {
#if __has_builtin(__builtin_amdgcn_permlane32_swap) && \
    __has_builtin(__builtin_amdgcn_permlane16_swap)
  uintx2 ab = __builtin_amdgcn_permlane32_swap(u, v, false, false);
  uintx2 fs = __builtin_amdgcn_permlane16_swap(ab[0], ab[1], false, false);
  f = fs[0];
  s = fs[1];
#else
  unsigned int a = (hi < 2) ? u : (unsigned int)__shfl_xor((int)v, 32);
  unsigned int b = (hi < 2) ? (unsigned int)__shfl_xor((int)u, 32) : v;
  unsigned int a16 = (unsigned int)__shfl_xor((int)a, 16);
  unsigned int b16 = (unsigned int)__shfl_xor((int)b, 16);
  f = (hi & 1) ? b16 : a;
  s = (hi & 1) ? b : a16;
#endif
}

// ---------------- prep: convert x + transpose 4 weights ----------------
__global__ __launch_bounds__(256) void prep_kernel(
    const float* __restrict__ x, bf16* __restrict__ xb,
    const float* __restrict__ wq, const float* __restrict__ wk,
    const float* __restrict__ wv, const float* __restrict__ wo,
    bf16* __restrict__ wT) {
  const int t = threadIdx.x;
  int bid = blockIdx.x;
  if (bid < 4096) {  // convert x: f32 -> bf16
    const int i = (bid * 256 + t) * 4;
    const float4 v = *(const float4*)(x + i);
    bf16x4 o;
    o[0] = (bf16)v.x; o[1] = (bf16)v.y; o[2] = (bf16)v.z; o[3] = (bf16)v.w;
    *(bf16x4*)(xb + i) = o;
    return;
  }
  bid -= 4096;
  const int sel = bid >> 8;  // 0..3 : wq wk wv wo
  const float* w = (sel == 0) ? wq : (sel == 1) ? wk : (sel == 2) ? wv : wo;
  bf16* out = wT + (size_t)sel * 1048576;
  __shared__ float tile[64][65];
  const int n0 = (bid & 15) * 64;
  const int k0 = ((bid >> 4) & 15) * 64;
#pragma unroll
  for (int p = 0; p < 4; ++p) {
    const int row = p * 16 + (t >> 4);
    const int c4  = (t & 15) * 4;
    const float4 v = *(const float4*)&w[(size_t)(k0 + row) * 1024 + n0 + c4];
    tile[row][c4 + 0] = v.x; tile[row][c4 + 1] = v.y;
    tile[row][c4 + 2] = v.z; tile[row][c4 + 3] = v.w;
  }
  __syncthreads();
#pragma unroll
  for (int p = 0; p < 4; ++p) {
    const int rn = p * 16 + (t >> 4);
    const int c4 = (t & 15) * 4;
    bf16x4 o;
#pragma unroll
    for (int j = 0; j < 4; ++j) o[j] = (bf16)tile[c4 + j][rn];
    *(bf16x4*)&out[(size_t)(n0 + rn) * 1024 + k0 + c4] = o;
  }
}

// ---------------- GEMM C = A[M][1024] * Bt[N][1024]^T ----------------
template <int MODE>
__global__ __launch_bounds__(256, 2) void gemm_bt(
    const bf16* __restrict__ A, const bf16* __restrict__ Bt,
    const float* __restrict__ bias0, const float* __restrict__ bias1,
    const float* __restrict__ bias2, bf16* __restrict__ qf,
    bf16* __restrict__ kf, bf16* __restrict__ vt, float* __restrict__ fout,
    int Nblocks) {
  __shared__ __align__(16) char smem[32768];
  char* sA = smem;
  char* sB = smem + 16384;
  const int tid = threadIdx.x;
  const int lane = tid & 63;
  const int w = tid >> 6;
  const int wm = w >> 1, wn = w & 1;
  const int bid = blockIdx.x;
  const int m0 = (bid / Nblocks) * 128;
  const int n0 = (bid % Nblocks) * 128;

  const char* Ab = (const char*)A;
  const char* Bb = (const char*)Bt;
  size_t srcA[4], srcB[4];
#pragma unroll
  for (int it = 0; it < 4; ++it) {
    const int o = it * 4096 + tid * 16;
    const int r = o >> 7;
    const int cg = ((o >> 4) & 7) ^ (r & 7);
    srcA[it] = (size_t)(m0 + r) * 2048 + cg * 16;
    srcB[it] = (size_t)(n0 + r) * 2048 + cg * 16;
  }

  f32x4 acc[4][4] = {};

  for (int kt = 0; kt < 16; ++kt) {
    const size_t kb = (size_t)kt * 128;
#pragma unroll
    for (int it = 0; it < 4; ++it) {
      load_lds16(Ab + srcA[it] + kb, sA + it * 4096 + w * 1024);
      load_lds16(Bb + srcB[it] + kb, sB + it * 4096 + w * 1024);
    }
    asm volatile("s_waitcnt vmcnt(0)" ::: "memory");
    __syncthreads();
#pragma unroll
    for (int ks = 0; ks < 2; ++ks) {
      bf16x8 aF[4], bF[4];
      const int g = (lane >> 4) + 4 * ks;
#pragma unroll
      for (int i = 0; i < 4; ++i) {
        const int ra = wm * 64 + i * 16 + (lane & 15);
        aF[i] = *(const bf16x8*)(sA + ra * 128 + ((g ^ (ra & 7)) << 4));
        const int rb = wn * 64 + i * 16 + (lane & 15);
        bF[i] = *(const bf16x8*)(sB + rb * 128 + ((g ^ (rb & 7)) << 4));
      }
#pragma unroll
      for (int mi = 0; mi < 4; ++mi)
#pragma unroll
        for (int ni = 0; ni < 4; ++ni)
          acc[mi][ni] = __builtin_amdgcn_mfma_f32_16x16x32_bf16(
              aF[mi], bF[ni], acc[mi][ni], 0, 0, 0);
    }
    __syncthreads();
  }

  const int cn = lane & 15;
  const int gq = lane >> 4;
#pragma unroll
  for (int mi = 0; mi < 4; ++mi) {
#pragma unroll
    for (int ni = 0; ni < 4; ++ni) {
      const int n  = n0 + wn * 64 + ni * 16 + cn;
      const int mb = m0 + wm * 64 + mi * 16 + 4 * gq;
      const f32x4 v = acc[mi][ni];
      if (MODE == 0) {
        const float bias =
            (n < 1024) ? bias0[n] : ((n < 2048) ? bias1[n - 1024] : bias2[n - 2048]);
        if (n < 2048) {
          bf16* dst = (n < 1024) ? qf : kf;
          const int nn = n & 1023;
#pragma unroll
          for (int j = 0; j < 4; ++j)
            dst[(size_t)(mb + j) * 1024 + nn] = (bf16)(v[j] + bias);
        } else {
          const int nn = n - 2048;
          const int hh = nn >> 6, dd = nn & 63;
          const int bb = mb >> 11, ss = mb & 2047;
          bf16x4 pk;
#pragma unroll
          for (int j = 0; j < 4; ++j) pk[j] = (bf16)(v[j] + bias);
          *(bf16x4*)(vt + ((size_t)((bb * 16 + hh) * 64 + dd) * 2048 + ss)) = pk;
        }
      } else {
        const float bias = bias0[n];
#pragma unroll
        for (int j = 0; j < 4; ++j)
          fout[(size_t)(mb + j) * 1024 + n] = v[j] + bias;
      }
    }
  }
}

// ---------------- flash attention v9 (valid keys: k > q) ----------------
// 512 blocks = 16 units x 32 bh; EVERY unit = exactly 17 k-tile-iters:
//   u<8 :       heavy jq=u,     k-tiles [2u, 2u+17)      mode 1 (partial)
//   u>=8, j=u-8: heavy jq=j,    k-tiles [2j+17, 32)      mode 2 (partial)
//            then light jq=15-j, k-tiles [30-2j, 32)     mode 0 (final)
// Uniform work -> balanced under ANY block->CU assignment; bh in low bits
// -> same-head blocks share one XCD's L2. 4 waves x 32 q-rows,
// in-register P, 2-buffer staging.
__global__ __launch_bounds__(256, 2) void attn_kernel(
    const bf16* __restrict__ qf, const bf16* __restrict__ kf,
    const bf16* __restrict__ vt, bf16* __restrict__ ao,
    bf16* __restrict__ o2buf, float* __restrict__ mlbuf) {
  __shared__ __align__(16) char smem[32768];  // sK[2][8192] | sV[2][8192]

  const int tid  = threadIdx.x;
  const int lane = tid & 63;
  const int hi   = lane >> 4;
  const int qlo  = lane & 15;
  const int w    = tid >> 6;
  const int u  = blockIdx.x >> 5;  // 0..15
  const int bh = blockIdx.x & 31;  // same-bh blocks share an XCD's L2
  const int b = bh >> 4, h = bh & 15;

  const char* kbase = (const char*)kf + ((size_t)b * 2048) * 2048 + h * 128;
  const char* vbase = (const char*)vt + (size_t)bh * 262144;
  const char* qbb   = (const char*)qf + ((size_t)b * 2048) * 2048 + h * 128;

  const int sr  = tid >> 3;              // staging row 0..31 (pass 2: +32)
  const int scg = (tid & 7) ^ (sr & 7);  // pre-swizzled source chunk

  bf16x8 onesB;
#pragma unroll
  for (int i = 0; i < 8; ++i) onesB[i] = (bf16)1.0f;

  // segment descriptors (block-uniform)
  int nseg, sjq[2], skb[2], ske[2], smode[2];
  if (u < 8) {
    nseg = 1;
    sjq[0] = u; skb[0] = 2 * u; ske[0] = 2 * u + 17; smode[0] = 1;
    sjq[1] = 0; skb[1] = 0; ske[1] = 0; smode[1] = 0;
  } else {
    const int j = u - 8;
    nseg = 2;
    sjq[0] = j;      skb[0] = 2 * j + 17; ske[0] = 32; smode[0] = 2;
    sjq[1] = 15 - j; skb[1] = 30 - 2 * j; ske[1] = 32; smode[1] = 0;
  }

  for (int seg = 0; seg < nseg; ++seg) {
    const int jq = sjq[seg], kbeg = skb[seg], kend = ske[seg];
    const int mode = smode[seg];

    const int q0 = jq * 128;
    const int qb = q0 + w * 32;

    // Q fragments for 2 column-tiles (pre-scaled by 1/8 -- exact in bf16)
    bf16x8 qA[2][2];
#pragma unroll
    for (int nt = 0; nt < 2; ++nt) {
      const char* qrow = qbb + (size_t)(qb + 16 * nt + qlo) * 2048;
#pragma unroll
      for (int ks = 0; ks < 2; ++ks) {
        qA[nt][ks] = *(const bf16x8*)(qrow + ks * 64 + hi * 16);
#pragma unroll
        for (int i = 0; i < 8; ++i)
          qA[nt][ks][i] = (bf16)(0.125f * (float)qA[nt][ks][i]);
      }
    }

    float m[2] = {-1e30f, -1e30f};
    f32x4 lacc[2] = {};
    f32x4 O[2][4] = {};

    // stage absolute k-tile kt into buffer bufi
    auto STAGE = [&](int kt, int bufi) {
      char* dK = smem + bufi * 8192 + w * 1024;
      char* dV = smem + 16384 + bufi * 8192 + w * 1024;
      const int kn = kt * 64;
#pragma unroll
      for (int p = 0; p < 2; ++p) {
        load_lds16(kbase + (size_t)(kn + sr + 32 * p) * 2048 + scg * 16,
                   dK + p * 4096);
        load_lds16(vbase + (size_t)(sr + 32 * p) * 4096 + (size_t)kn * 2 +
                       scg * 16,
                   dV + p * 4096);
      }
    };

    STAGE(kbeg, 0);
    __syncthreads();

    for (int kt = kbeg; kt < kend; ++kt) {
      const int cur = (kt - kbeg) & 1;

      // issue next-tile staging (drains at this iteration's closing barrier)
      if (kt + 1 < kend) STAGE(kt + 1, cur ^ 1);

      const char* bK = smem + cur * 8192;
      const char* bV = smem + 16384 + cur * 8192;

      // QK^T swapped: sc[nt][t] rows = k (16t+4hi+j), col = q (16nt+qlo);
      // kF shared across both nt tiles.
      f32x4 sc[2][4] = {};
#pragma unroll
      for (int ks = 0; ks < 2; ++ks) {
        const int gg = hi + 4 * ks;
#pragma unroll
        for (int t = 0; t < 4; ++t) {
          const int rk = t * 16 + qlo;
          const bf16x8 kF =
              *(const bf16x8*)(bK + rk * 128 + ((gg ^ (rk & 7)) << 4));
          sc[0][t] = __builtin_amdgcn_mfma_f32_16x16x32_bf16(kF, qA[0][ks],
                                                             sc[0][t], 0, 0, 0);
          sc[1][t] = __builtin_amdgcn_mfma_f32_16x16x32_bf16(kF, qA[1][ks],
                                                             sc[1][t], 0, 0, 0);
        }
      }

      if (kt * 64 < q0 + 128) {  // tiles overlapping the q-range: mask k <= q
        const int k0t = kt * 64;
#pragma unroll
        for (int nt = 0; nt < 2; ++nt)
#pragma unroll
          for (int t = 0; t < 4; ++t)
#pragma unroll
            for (int j = 0; j < 4; ++j) {
              const int kk = k0t + t * 16 + 4 * hi + j;
              const int qq = qb + 16 * nt + qlo;
              if (kk <= qq) sc[nt][t][j] = -1e30f;
            }
      }

      // per-q tile max (lane-local 16 vals + 2 shfl)
      float tm[2];
#pragma unroll
      for (int nt = 0; nt < 2; ++nt) {
        float v = sc[nt][0][0];
#pragma unroll
        for (int t = 0; t < 4; ++t)
#pragma unroll
          for (int j = 0; j < 4; ++j) v = fmaxf(v, sc[nt][t][j]);
        v = fmaxf(v, __shfl_xor(v, 16));
        v = fmaxf(v, __shfl_xor(v, 32));
        tm[nt] = v;
      }

      // T13 defer-max: rescale only when some row's max grew by > 8
      const bool grew = (tm[0] - m[0] > 8.0f) || (tm[1] - m[1] > 8.0f);
      if (__any(grew)) {
#pragma unroll
        for (int nt = 0; nt < 2; ++nt) {
          const float mn = fmaxf(m[nt], tm[nt]);
          const float al = __expf(m[nt] - mn);
          m[nt] = mn;
#pragma unroll
          for (int j = 0; j < 4; ++j) {
            const float alj = __shfl(al, 4 * hi + j);
            lacc[nt][j] *= alj;
#pragma unroll
            for (int dt = 0; dt < 4; ++dt) O[nt][dt][j] *= alj;
          }
        }
      }

      // P = exp(s - m) packed to bf16 pairs, redistributed in-register to
      // the PV A-fragment layout (no LDS round-trip).
      bf16x8 pA[2][2];
#pragma unroll
      for (int nt = 0; nt < 2; ++nt) {
        unsigned int W[4][2];
#pragma unroll
        for (int t = 0; t < 4; ++t)
#pragma unroll
          for (int p = 0; p < 2; ++p)
            W[t][p] = packbf(__expf(sc[nt][t][2 * p] - m[nt]),
                             __expf(sc[nt][t][2 * p + 1] - m[nt]));
#pragma unroll
        for (int ks = 0; ks < 2; ++ks) {
          uintx4 w4;
#pragma unroll
          for (int p = 0; p < 2; ++p) {
            unsigned int f, s;
            xchg_p(W[2 * ks][p], W[2 * ks + 1][p], hi, f, s);
            w4[p] = f;
            w4[2 + p] = s;
          }
          pA[nt][ks] = __builtin_bit_cast(bf16x8, w4);
          lacc[nt] = __builtin_amdgcn_mfma_f32_16x16x32_bf16(pA[nt][ks], onesB,
                                                             lacc[nt], 0, 0, 0);
        }
      }

      // PV: O[q][d] += P*V ; vF shared across both nt tiles
#pragma unroll
      for (int ks = 0; ks < 2; ++ks) {
        const int gg = hi + 4 * ks;
#pragma unroll
        for (int dt = 0; dt < 4; ++dt) {
          const int rv = dt * 16 + qlo;
          const bf16x8 vF =
              *(const bf16x8*)(bV + rv * 128 + ((gg ^ (rv & 7)) << 4));
          O[0][dt] = __builtin_amdgcn_mfma_f32_16x16x32_bf16(pA[0][ks], vF,
                                                             O[0][dt], 0, 0, 0);
          O[1][dt] = __builtin_amdgcn_mfma_f32_16x16x32_bf16(pA[1][ks], vF,
                                                             O[1][dt], 0, 0, 0);
        }
      }
      __syncthreads();
    }

    if (mode == 0) {
      // normalized write (O rows 4*hi+j; lacc[j] same rows -> lane-local)
#pragma unroll
      for (int nt = 0; nt < 2; ++nt)
#pragma unroll
        for (int j = 0; j < 4; ++j) {
          const float linv = (lacc[nt][j] > 0.f) ? 1.f / lacc[nt][j] : 0.f;
          const int qg = qb + 16 * nt + 4 * hi + j;
#pragma unroll
          for (int dt = 0; dt < 4; ++dt)
            ao[(size_t)(b * 2048 + qg) * 1024 + h * 64 + dt * 16 + qlo] =
                (bf16)(O[nt][dt][j] * linv);
        }
    } else {
      // flash partial write: unnormalized O (bf16) + m,l (f32)
      const int qtbh = jq * 32 + bh;
      const int slot = mode - 1;
#pragma unroll
      for (int nt = 0; nt < 2; ++nt)
#pragma unroll
        for (int j = 0; j < 4; ++j) {
          const int r = w * 32 + 16 * nt + 4 * hi + j;  // row within q-tile
#pragma unroll
          for (int dt = 0; dt < 4; ++dt) {
            const bf16 vv = (bf16)O[nt][dt][j];
            if (mode == 1)
              ao[(size_t)(b * 2048 + q0 + r) * 1024 + h * 64 + dt * 16 + qlo] =
                  vv;
            else
              o2buf[(size_t)(qtbh * 128 + r) * 64 + dt * 16 + qlo] = vv;
          }
        }
      if (qlo == 0) {
#pragma unroll
        for (int nt = 0; nt < 2; ++nt)
#pragma unroll
          for (int j = 0; j < 4; ++j)
            mlbuf[((qtbh * 2 + slot) * 2 + 1) * 128 +
                  (w * 32 + 16 * nt + 4 * hi + j)] = lacc[nt][j];
      }
      if (hi == 0) {
#pragma unroll
        for (int nt = 0; nt < 2; ++nt)
          mlbuf[((qtbh * 2 + slot) * 2 + 0) * 128 + (w * 32 + 16 * nt + qlo)] =
              m[nt];
      }
    }
    __syncthreads();  // protect smem reuse across segments
  }
}

// ---------------- combine: merge the two k-chunk partials (jq=0..7) -------
__global__ __launch_bounds__(256) void combine_kernel(
    const bf16* __restrict__ o2buf, const float* __restrict__ mlbuf,
    bf16* __restrict__ ao) {
  const int qtbh = blockIdx.x;  // jq*32 + bh, jq in 0..7
  const int jq = qtbh >> 5, bh = qtbh & 31;
  const int b = bh >> 4, h = bh & 15;
  const int t = threadIdx.x;
  const int r = t >> 1;
  const int c0 = (t & 1) * 32;

  const float m1 = mlbuf[((qtbh * 2 + 0) * 2 + 0) * 128 + r];
  const float l1 = mlbuf[((qtbh * 2 + 0) * 2 + 1) * 128 + r];
  const float m2 = mlbuf[((qtbh * 2 + 1) * 2 + 0) * 128 + r];
  const float l2 = mlbuf[((qtbh * 2 + 1) * 2 + 1) * 128 + r];
  const float M  = fmaxf(m1, m2);
  const float w1 = __expf(m1 - M), w2 = __expf(m2 - M);
  const float denom = w1 * l1 + w2 * l2;
  const float linv = (denom > 0.f) ? 1.f / denom : 0.f;

  bf16* arow = ao + ((size_t)(b * 2048 + jq * 128 + r) * 1024 + h * 64 + c0);
  const bf16* o2row = o2buf + ((size_t)(qtbh * 128 + r) * 64 + c0);
#pragma unroll
  for (int i = 0; i < 4; ++i) {
    const bf16x8 o1 = *(const bf16x8*)(arow + i * 8);
    const bf16x8 o2 = *(const bf16x8*)(o2row + i * 8);
    bf16x8 o;
#pragma unroll
    for (int j = 0; j < 8; ++j)
      o[j] = (bf16)((w1 * (float)o1[j] + w2 * (float)o2[j]) * linv);
    *(bf16x8*)(arow + i * 8) = o;
  }
}

// ---------------- last-row fix: ao[q=2047] = mean over s of V ----------------
__global__ __launch_bounds__(256) void vmean_kernel(const bf16* __restrict__ vt,
                                                    bf16* __restrict__ ao) {
  const int tid = threadIdx.x;
  const int lane = tid & 63, w = tid >> 6;
  const int gw = blockIdx.x * 4 + w;  // 0..2047 == bh*64 + d
  const int bh = gw >> 6, d = gw & 63;
  const int b = bh >> 4, h = bh & 15;
  const bf16x8* p = (const bf16x8*)(vt + (size_t)gw * 2048 + lane * 32);
  float s = 0.f;
#pragma unroll
  for (int i = 0; i < 4; ++i) {
    const bf16x8 v = p[i];
#pragma unroll
    for (int j = 0; j < 8; ++j) s += (float)v[j];
  }
  for (int off = 1; off < 64; off <<= 1) s += __shfl_xor(s, off);
  if (lane == 0)
    ao[(size_t)(b * 2048 + 2047) * 1024 + h * 64 + d] = (bf16)(s * (1.f / 2048.f));
}

extern "C" void kernel_launch(void* const* d_in, const int* in_sizes, int n_in,
                              void* d_out, int out_size, void* d_ws,
                              size_t ws_size, hipStream_t stream) {
  const float* x  = (const float*)d_in[0];
  const float* wq = (const float*)d_in[2];
  const float* bq = (const float*)d_in[3];
  const float* wk = (const float*)d_in[4];
  const float* bk = (const float*)d_in[5];
  const float* wv = (const float*)d_in[6];
  const float* bv = (const float*)d_in[7];
  const float* wo = (const float*)d_in[8];
  const float* bo = (const float*)d_in[9];
  float* out = (float*)d_out;

  if (ws_size < (size_t)25165824 * 2) return;  // need ~48 MiB of scratch

  bf16* ws    = (bf16*)d_ws;
  bf16* xb    = ws;                     // [4096][1024]; reused as partials
  bf16* wqkvT = xb + 4194304;           // [3072][1024]
  bf16* woT   = wqkvT + 3145728;        // [1024][1024]
  bf16* qfp   = woT + 1048576;          // [4096][1024] flat
  bf16* kfp   = qfp + 4194304;          // [4096][1024] flat
  bf16* vtp   = kfp + 4194304;          // [b][h][d][s]
  bf16* aop   = vtp + 4194304;          // [4096][1024] flat

  // partial scratch (xb is dead after the QKV GEMM):
  bf16*  o2buf = xb;                         // 8qt*32bh*128*64 bf16 = 4 MiB
  float* mlbuf = (float*)(xb + 2097152);     // 8*32*2*2*128 f32 = 512 KiB

  prep_kernel<<<5120, 256, 0, stream>>>(x, xb, wq, wk, wv, wo, wqkvT);

  gemm_bt<0><<<32 * 24, 256, 0, stream>>>(xb, wqkvT, bq, bk, bv, qfp, kfp, vtp,
                                          nullptr, 24);
  attn_kernel<<<512, 256, 0, stream>>>(qfp, kfp, vtp, aop, o2buf, mlbuf);
  vmean_kernel<<<512, 256, 0, stream>>>(vtp, aop);
  combine_kernel<<<256, 256, 0, stream>>>(o2buf, mlbuf, aop);
  gemm_bt<1><<<32 * 8, 256, 0, stream>>>(aop, woT, bo, nullptr, nullptr, nullptr,
                                         nullptr, nullptr, out, 8);
}

// Round 10
// 105.993 us; speedup vs baseline: 1.1423x; 1.0190x over previous
//
#include <hip/hip_runtime.h>
#include <hip/hip_bf16.h>

// MaskedSelfAttention: B=2, S=2048, D=1024, H=16, depth=64.
// prep (convert+transpose) -> fused QKV GEMM (K/V written in MFMA-fragment
// layout) -> flash attn (barrier-free, LDS-free; anti-causal: valid k>q;
// q=2047 row = mean(V) via vmean) -> combine -> out GEMM.
// R10: K/V stored as KF[bh][kt][t][ks][lane][e] / VF[bh][kt][dt][ks][lane][e]
// so attn waves load fragments as coalesced 1KB global loads from L2 —
// no LDS staging, no __syncthreads in the loop (R9 lesson: the barrier
// convoy, not makespan, was the ~3300 cyc/iter cost).

using bf16   = __bf16;
using bf16x2 = __attribute__((ext_vector_type(2))) __bf16;
using bf16x4 = __attribute__((ext_vector_type(4))) __bf16;
using bf16x8 = __attribute__((ext_vector_type(8))) __bf16;
using f32x4  = __attribute__((ext_vector_type(4))) float;
using uintx2 = __attribute__((ext_vector_type(2))) unsigned int;
using uintx4 = __attribute__((ext_vector_type(4))) unsigned int;

__device__ __forceinline__ void load_lds16(const void* g, void* l) {
  __builtin_amdgcn_global_load_lds(
      (const __attribute__((address_space(1))) void*)g,
      (__attribute__((address_space(3))) void*)l, 16, 0, 0);
}

__device__ __forceinline__ unsigned int packbf(float a, float b) {
  bf16x2 v;
  v[0] = (bf16)a;
  v[1] = (bf16)b;
  return __builtin_bit_cast(unsigned int, v);
}

// Redistribute packed P words across hi-groups (in-register P, R4).
__device__ __forceinline__ void xchg_p(unsigned int u, unsigned int v, int hi,
                                       unsigned int& f, unsigned int& s) {
#if __has_builtin(__builtin_amdgcn_permlane32_swap) && \
    __has_builtin(__builtin_amdgcn_permlane16_swap)
  uintx2 ab = __builtin_amdgcn_permlane32_swap(u, v, false, false);
  uintx2 fs = __builtin_amdgcn_permlane16_swap(ab[0], ab[1], false, false);
  f = fs[0];
  s = fs[1];
#else
  unsigned int a = (hi < 2) ? u : (unsigned int)__shfl_xor((int)v, 32);
  unsigned int b = (hi < 2) ? (unsigned int)__shfl_xor((int)u, 32) : v;
  unsigned int a16 = (unsigned int)__shfl_xor((int)a, 16);
  unsigned int b16 = (unsigned int)__shfl_xor((int)b, 16);
  f = (hi & 1) ? b16 : a;
  s = (hi & 1) ? b : a16;
#endif
}

// ---------------- prep: convert x + transpose 4 weights ----------------
__global__ __launch_bounds__(256) void prep_kernel(
    const float* __restrict__ x, bf16* __restrict__ xb,
    const float* __restrict__ wq, const float* __restrict__ wk,
    const float* __restrict__ wv, const float* __restrict__ wo,
    bf16* __restrict__ wT) {
  const int t = threadIdx.x;
  int bid = blockIdx.x;
  if (bid < 4096) {  // convert x: f32 -> bf16
    const int i = (bid * 256 + t) * 4;
    const float4 v = *(const float4*)(x + i);
    bf16x4 o;
    o[0] = (bf16)v.x; o[1] = (bf16)v.y; o[2] = (bf16)v.z; o[3] = (bf16)v.w;
    *(bf16x4*)(xb + i) = o;
    return;
  }
  bid -= 4096;
  const int sel = bid >> 8;  // 0..3 : wq wk wv wo
  const float* w = (sel == 0) ? wq : (sel == 1) ? wk : (sel == 2) ? wv : wo;
  bf16* out = wT + (size_t)sel * 1048576;
  __shared__ float tile[64][65];
  const int n0 = (bid & 15) * 64;
  const int k0 = ((bid >> 4) & 15) * 64;
#pragma unroll
  for (int p = 0; p < 4; ++p) {
    const int row = p * 16 + (t >> 4);
    const int c4  = (t & 15) * 4;
    const float4 v = *(const float4*)&w[(size_t)(k0 + row) * 1024 + n0 + c4];
    tile[row][c4 + 0] = v.x; tile[row][c4 + 1] = v.y;
    tile[row][c4 + 2] = v.z; tile[row][c4 + 3] = v.w;
  }
  __syncthreads();
#pragma unroll
  for (int p = 0; p < 4; ++p) {
    const int rn = p * 16 + (t >> 4);
    const int c4 = (t & 15) * 4;
    bf16x4 o;
#pragma unroll
    for (int j = 0; j < 4; ++j) o[j] = (bf16)tile[c4 + j][rn];
    *(bf16x4*)&out[(size_t)(n0 + rn) * 1024 + k0 + c4] = o;
  }
}

// ---------------- GEMM C = A[M][1024] * Bt[N][1024]^T ----------------
// MODE 0: fused QKV. Q -> flat [4096][1024]; K -> KF fragment layout;
//         V -> VF fragment layout (see header comment).
// MODE 1: out GEMM, f32 + bias.
template <int MODE>
__global__ __launch_bounds__(256, 2) void gemm_bt(
    const bf16* __restrict__ A, const bf16* __restrict__ Bt,
    const float* __restrict__ bias0, const float* __restrict__ bias1,
    const float* __restrict__ bias2, bf16* __restrict__ qf,
    bf16* __restrict__ kfr, bf16* __restrict__ vfr, float* __restrict__ fout,
    int Nblocks) {
  __shared__ __align__(16) char smem[32768];
  char* sA = smem;
  char* sB = smem + 16384;
  const int tid = threadIdx.x;
  const int lane = tid & 63;
  const int w = tid >> 6;
  const int wm = w >> 1, wn = w & 1;
  const int bid = blockIdx.x;
  const int m0 = (bid / Nblocks) * 128;
  const int n0 = (bid % Nblocks) * 128;

  const char* Ab = (const char*)A;
  const char* Bb = (const char*)Bt;
  size_t srcA[4], srcB[4];
#pragma unroll
  for (int it = 0; it < 4; ++it) {
    const int o = it * 4096 + tid * 16;
    const int r = o >> 7;
    const int cg = ((o >> 4) & 7) ^ (r & 7);
    srcA[it] = (size_t)(m0 + r) * 2048 + cg * 16;
    srcB[it] = (size_t)(n0 + r) * 2048 + cg * 16;
  }

  f32x4 acc[4][4] = {};

  for (int kt = 0; kt < 16; ++kt) {
    const size_t kb = (size_t)kt * 128;
#pragma unroll
    for (int it = 0; it < 4; ++it) {
      load_lds16(Ab + srcA[it] + kb, sA + it * 4096 + w * 1024);
      load_lds16(Bb + srcB[it] + kb, sB + it * 4096 + w * 1024);
    }
    asm volatile("s_waitcnt vmcnt(0)" ::: "memory");
    __syncthreads();
#pragma unroll
    for (int ks = 0; ks < 2; ++ks) {
      bf16x8 aF[4], bF[4];
      const int g = (lane >> 4) + 4 * ks;
#pragma unroll
      for (int i = 0; i < 4; ++i) {
        const int ra = wm * 64 + i * 16 + (lane & 15);
        aF[i] = *(const bf16x8*)(sA + ra * 128 + ((g ^ (ra & 7)) << 4));
        const int rb = wn * 64 + i * 16 + (lane & 15);
        bF[i] = *(const bf16x8*)(sB + rb * 128 + ((g ^ (rb & 7)) << 4));
      }
#pragma unroll
      for (int mi = 0; mi < 4; ++mi)
#pragma unroll
        for (int ni = 0; ni < 4; ++ni)
          acc[mi][ni] = __builtin_amdgcn_mfma_f32_16x16x32_bf16(
              aF[mi], bF[ni], acc[mi][ni], 0, 0, 0);
    }
    __syncthreads();
  }

  const int cn = lane & 15;
  const int gq = lane >> 4;
#pragma unroll
  for (int mi = 0; mi < 4; ++mi) {
#pragma unroll
    for (int ni = 0; ni < 4; ++ni) {
      const int n  = n0 + wn * 64 + ni * 16 + cn;
      const int mb = m0 + wm * 64 + mi * 16 + 4 * gq;
      const f32x4 v = acc[mi][ni];
      if (MODE == 0) {
        const float bias =
            (n < 1024) ? bias0[n] : ((n < 2048) ? bias1[n - 1024] : bias2[n - 2048]);
        if (n < 1024) {  // Q flat
#pragma unroll
          for (int j = 0; j < 4; ++j)
            qf[(size_t)(mb + j) * 1024 + n] = (bf16)(v[j] + bias);
        } else if (n < 2048) {  // K fragment layout
          const int dg = n - 1024;
          const int hh = dg >> 6, d = dg & 63;
          const int ks = d >> 5, hl = (d >> 3) & 3, e = d & 7;
          const int bb = mb >> 11, sl = mb & 2047;
          const int ktt = sl >> 6, tt = (sl >> 4) & 3, ql = sl & 15;
          bf16* dst = kfr +
                      ((((size_t)(bb * 16 + hh) * 32 + ktt) * 4 + tt) * 2 + ks) *
                          512 +
                      (hl * 16 + ql) * 8 + e;
#pragma unroll
          for (int j = 0; j < 4; ++j) dst[j * 8] = (bf16)(v[j] + bias);
        } else {  // V fragment layout (8B packed store)
          const int dg = n - 2048;
          const int hh = dg >> 6, d = dg & 63;
          const int dt = d >> 4, dc = d & 15;
          const int bb = mb >> 11, sl = mb & 2047;
          const int ktt = sl >> 6, ks = (sl >> 5) & 1, hl = (sl >> 3) & 3,
                    e0 = sl & 7;
          bf16x4 pk;
#pragma unroll
          for (int j = 0; j < 4; ++j) pk[j] = (bf16)(v[j] + bias);
          *(bf16x4*)(vfr +
                     ((((size_t)(bb * 16 + hh) * 32 + ktt) * 4 + dt) * 2 + ks) *
                         512 +
                     (hl * 16 + dc) * 8 + e0) = pk;
        }
      } else {
        const float bias = bias0[n];
#pragma unroll
        for (int j = 0; j < 4; ++j)
          fout[(size_t)(mb + j) * 1024 + n] = v[j] + bias;
      }
    }
  }
}

// ---------------- flash attention v10 (valid keys: k > q) ----------------
// 512 blocks = 16 units x 32 bh; EVERY unit = exactly 17 k-tile-iters (R9
// partition). NO LDS, NO barriers: K/V fragments loaded directly from the
// precomputed KF/VF layouts (coalesced 1KB loads, L2-resident). 4 waves x
// 32 q-rows, in-register P, defer-max.
__global__ __launch_bounds__(256, 2) void attn_kernel(
    const bf16* __restrict__ qf, const bf16* __restrict__ kfr,
    const bf16* __restrict__ vfr, bf16* __restrict__ ao,
    bf16* __restrict__ o2buf, float* __restrict__ mlbuf) {
  const int tid  = threadIdx.x;
  const int lane = tid & 63;
  const int hi   = lane >> 4;
  const int qlo  = lane & 15;
  const int w    = tid >> 6;
  const int u  = blockIdx.x >> 5;  // 0..15
  const int bh = blockIdx.x & 31;  // same-bh blocks share an XCD's L2
  const int b = bh >> 4, h = bh & 15;

  const char* kfb = (const char*)kfr + (size_t)bh * 262144 + lane * 16;
  const char* vfb = (const char*)vfr + (size_t)bh * 262144 + lane * 16;
  const char* qbb = (const char*)qf + ((size_t)b * 2048) * 2048 + h * 128;

  bf16x8 onesB;
#pragma unroll
  for (int i = 0; i < 8; ++i) onesB[i] = (bf16)1.0f;

  // segment descriptors (block-uniform); every block = 17 iters total
  int nseg, sjq[2], skb[2], ske[2], smode[2];
  if (u < 8) {
    nseg = 1;
    sjq[0] = u; skb[0] = 2 * u; ske[0] = 2 * u + 17; smode[0] = 1;
    sjq[1] = 0; skb[1] = 0; ske[1] = 0; smode[1] = 0;
  } else {
    const int j = u - 8;
    nseg = 2;
    sjq[0] = j;      skb[0] = 2 * j + 17; ske[0] = 32; smode[0] = 2;
    sjq[1] = 15 - j; skb[1] = 30 - 2 * j; ske[1] = 32; smode[1] = 0;
  }

  for (int seg = 0; seg < nseg; ++seg) {
    const int jq = sjq[seg], kbeg = skb[seg], kend = ske[seg];
    const int mode = smode[seg];

    const int q0 = jq * 128;
    const int qb = q0 + w * 32;

    // Q fragments for 2 column-tiles (pre-scaled by 1/8 -- exact in bf16)
    bf16x8 qA[2][2];
#pragma unroll
    for (int nt = 0; nt < 2; ++nt) {
      const char* qrow = qbb + (size_t)(qb + 16 * nt + qlo) * 2048;
#pragma unroll
      for (int ks = 0; ks < 2; ++ks) {
        qA[nt][ks] = *(const bf16x8*)(qrow + ks * 64 + hi * 16);
#pragma unroll
        for (int i = 0; i < 8; ++i)
          qA[nt][ks][i] = (bf16)(0.125f * (float)qA[nt][ks][i]);
      }
    }

    float m[2] = {-1e30f, -1e30f};
    f32x4 lacc[2] = {};
    f32x4 O[2][4] = {};

    for (int kt = kbeg; kt < kend; ++kt) {
      // direct fragment loads (coalesced 1KB each; L2-resident)
      const char* kT = kfb + (size_t)kt * 8192;
      const char* vT = vfb + (size_t)kt * 8192;
      bf16x8 kFr[2][4], vFr[2][4];
#pragma unroll
      for (int ks = 0; ks < 2; ++ks)
#pragma unroll
        for (int t = 0; t < 4; ++t)
          kFr[ks][t] = *(const bf16x8*)(kT + (t * 2 + ks) * 1024);
#pragma unroll
      for (int ks = 0; ks < 2; ++ks)
#pragma unroll
        for (int dt = 0; dt < 4; ++dt)
          vFr[ks][dt] = *(const bf16x8*)(vT + (dt * 2 + ks) * 1024);

      // QK^T swapped: sc[nt][t] rows = k (16t+4hi+j), col = q (16nt+qlo)
      f32x4 sc[2][4] = {};
#pragma unroll
      for (int ks = 0; ks < 2; ++ks)
#pragma unroll
        for (int t = 0; t < 4; ++t) {
          sc[0][t] = __builtin_amdgcn_mfma_f32_16x16x32_bf16(
              kFr[ks][t], qA[0][ks], sc[0][t], 0, 0, 0);
          sc[1][t] = __builtin_amdgcn_mfma_f32_16x16x32_bf16(
              kFr[ks][t], qA[1][ks], sc[1][t], 0, 0, 0);
        }

      if (kt * 64 < q0 + 128) {  // tiles overlapping the q-range: mask k <= q
        const int k0t = kt * 64;
#pragma unroll
        for (int nt = 0; nt < 2; ++nt)
#pragma unroll
          for (int t = 0; t < 4; ++t)
#pragma unroll
            for (int j = 0; j < 4; ++j) {
              const int kk = k0t + t * 16 + 4 * hi + j;
              const int qq = qb + 16 * nt + qlo;
              if (kk <= qq) sc[nt][t][j] = -1e30f;
            }
      }

      // per-q tile max (lane-local 16 vals + 2 shfl)
      float tm[2];
#pragma unroll
      for (int nt = 0; nt < 2; ++nt) {
        float v = sc[nt][0][0];
#pragma unroll
        for (int t = 0; t < 4; ++t)
#pragma unroll
          for (int j = 0; j < 4; ++j) v = fmaxf(v, sc[nt][t][j]);
        v = fmaxf(v, __shfl_xor(v, 16));
        v = fmaxf(v, __shfl_xor(v, 32));
        tm[nt] = v;
      }

      // T13 defer-max: rescale only when some row's max grew by > 8
      const bool grew = (tm[0] - m[0] > 8.0f) || (tm[1] - m[1] > 8.0f);
      if (__any(grew)) {
#pragma unroll
        for (int nt = 0; nt < 2; ++nt) {
          const float mn = fmaxf(m[nt], tm[nt]);
          const float al = __expf(m[nt] - mn);
          m[nt] = mn;
#pragma unroll
          for (int j = 0; j < 4; ++j) {
            const float alj = __shfl(al, 4 * hi + j);
            lacc[nt][j] *= alj;
#pragma unroll
            for (int dt = 0; dt < 4; ++dt) O[nt][dt][j] *= alj;
          }
        }
      }

      // P = exp(s - m) packed to bf16 pairs, redistributed in-register
      bf16x8 pA[2][2];
#pragma unroll
      for (int nt = 0; nt < 2; ++nt) {
        unsigned int W[4][2];
#pragma unroll
        for (int t = 0; t < 4; ++t)
#pragma unroll
          for (int p = 0; p < 2; ++p)
            W[t][p] = packbf(__expf(sc[nt][t][2 * p] - m[nt]),
                             __expf(sc[nt][t][2 * p + 1] - m[nt]));
#pragma unroll
        for (int ks = 0; ks < 2; ++ks) {
          uintx4 w4;
#pragma unroll
          for (int p = 0; p < 2; ++p) {
            unsigned int f, s;
            xchg_p(W[2 * ks][p], W[2 * ks + 1][p], hi, f, s);
            w4[p] = f;
            w4[2 + p] = s;
          }
          pA[nt][ks] = __builtin_bit_cast(bf16x8, w4);
          lacc[nt] = __builtin_amdgcn_mfma_f32_16x16x32_bf16(pA[nt][ks], onesB,
                                                             lacc[nt], 0, 0, 0);
        }
      }

      // PV: O[q][d] += P*V
#pragma unroll
      for (int ks = 0; ks < 2; ++ks)
#pragma unroll
        for (int dt = 0; dt < 4; ++dt) {
          O[0][dt] = __builtin_amdgcn_mfma_f32_16x16x32_bf16(
              pA[0][ks], vFr[ks][dt], O[0][dt], 0, 0, 0);
          O[1][dt] = __builtin_amdgcn_mfma_f32_16x16x32_bf16(
              pA[1][ks], vFr[ks][dt], O[1][dt], 0, 0, 0);
        }
    }

    if (mode == 0) {
      // normalized write (O rows 4*hi+j; lacc[j] same rows -> lane-local)
#pragma unroll
      for (int nt = 0; nt < 2; ++nt)
#pragma unroll
        for (int j = 0; j < 4; ++j) {
          const float linv = (lacc[nt][j] > 0.f) ? 1.f / lacc[nt][j] : 0.f;
          const int qg = qb + 16 * nt + 4 * hi + j;
#pragma unroll
          for (int dt = 0; dt < 4; ++dt)
            ao[(size_t)(b * 2048 + qg) * 1024 + h * 64 + dt * 16 + qlo] =
                (bf16)(O[nt][dt][j] * linv);
        }
    } else {
      // flash partial write: unnormalized O (bf16) + m,l (f32)
      const int qtbh = jq * 32 + bh;
      const int slot = mode - 1;
#pragma unroll
      for (int nt = 0; nt < 2; ++nt)
#pragma unroll
        for (int j = 0; j < 4; ++j) {
          const int r = w * 32 + 16 * nt + 4 * hi + j;  // row within q-tile
#pragma unroll
          for (int dt = 0; dt < 4; ++dt) {
            const bf16 vv = (bf16)O[nt][dt][j];
            if (mode == 1)
              ao[(size_t)(b * 2048 + q0 + r) * 1024 + h * 64 + dt * 16 + qlo] =
                  vv;
            else
              o2buf[(size_t)(qtbh * 128 + r) * 64 + dt * 16 + qlo] = vv;
          }
        }
      if (qlo == 0) {
#pragma unroll
        for (int nt = 0; nt < 2; ++nt)
#pragma unroll
          for (int j = 0; j < 4; ++j)
            mlbuf[((qtbh * 2 + slot) * 2 + 1) * 128 +
                  (w * 32 + 16 * nt + 4 * hi + j)] = lacc[nt][j];
      }
      if (hi == 0) {
#pragma unroll
        for (int nt = 0; nt < 2; ++nt)
          mlbuf[((qtbh * 2 + slot) * 2 + 0) * 128 + (w * 32 + 16 * nt + qlo)] =
              m[nt];
      }
    }
  }
}

// ---------------- combine: merge the two k-chunk partials (jq=0..7) -------
__global__ __launch_bounds__(256) void combine_kernel(
    const bf16* __restrict__ o2buf, const float* __restrict__ mlbuf,
    bf16* __restrict__ ao) {
  const int qtbh = blockIdx.x;  // jq*32 + bh, jq in 0..7
  const int jq = qtbh >> 5, bh = qtbh & 31;
  const int b = bh >> 4, h = bh & 15;
  const int t = threadIdx.x;
  const int r = t >> 1;
  const int c0 = (t & 1) * 32;

  const float m1 = mlbuf[((qtbh * 2 + 0) * 2 + 0) * 128 + r];
  const float l1 = mlbuf[((qtbh * 2 + 0) * 2 + 1) * 128 + r];
  const float m2 = mlbuf[((qtbh * 2 + 1) * 2 + 0) * 128 + r];
  const float l2 = mlbuf[((qtbh * 2 + 1) * 2 + 1) * 128 + r];
  const float M  = fmaxf(m1, m2);
  const float w1 = __expf(m1 - M), w2 = __expf(m2 - M);
  const float denom = w1 * l1 + w2 * l2;
  const float linv = (denom > 0.f) ? 1.f / denom : 0.f;

  bf16* arow = ao + ((size_t)(b * 2048 + jq * 128 + r) * 1024 + h * 64 + c0);
  const bf16* o2row = o2buf + ((size_t)(qtbh * 128 + r) * 64 + c0);
#pragma unroll
  for (int i = 0; i < 4; ++i) {
    const bf16x8 o1 = *(const bf16x8*)(arow + i * 8);
    const bf16x8 o2 = *(const bf16x8*)(o2row + i * 8);
    bf16x8 o;
#pragma unroll
    for (int j = 0; j < 8; ++j)
      o[j] = (bf16)((w1 * (float)o1[j] + w2 * (float)o2[j]) * linv);
    *(bf16x8*)(arow + i * 8) = o;
  }
}

// ---------------- last-row fix: ao[q=2047] = mean over s of V --------------
// Reads the VF fragment layout: wave gw covers (bh = gw>>2, dt = gw&3).
__global__ __launch_bounds__(256) void vmean_kernel(const bf16* __restrict__ vfr,
                                                    bf16* __restrict__ ao) {
  const int tid = threadIdx.x;
  const int lane = tid & 63, w = tid >> 6;
  const int gw = blockIdx.x * 4 + w;  // 0..127
  const int bh = gw >> 2, dt = gw & 3;
  const int b = bh >> 4, h = bh & 15;
  const char* vfb = (const char*)vfr + (size_t)bh * 262144 + lane * 16;
  float s = 0.f;
  for (int kt = 0; kt < 32; ++kt) {
#pragma unroll
    for (int ks = 0; ks < 2; ++ks) {
      const bf16x8 v =
          *(const bf16x8*)(vfb + (size_t)kt * 8192 + (dt * 2 + ks) * 1024);
#pragma unroll
      for (int e = 0; e < 8; ++e) s += (float)v[e];
    }
  }
  s += __shfl_xor(s, 16);
  s += __shfl_xor(s, 32);
  if ((lane >> 4) == 0)
    ao[(size_t)(b * 2048 + 2047) * 1024 + h * 64 + dt * 16 + lane] =
        (bf16)(s * (1.f / 2048.f));
}

extern "C" void kernel_launch(void* const* d_in, const int* in_sizes, int n_in,
                              void* d_out, int out_size, void* d_ws,
                              size_t ws_size, hipStream_t stream) {
  const float* x  = (const float*)d_in[0];
  const float* wq = (const float*)d_in[2];
  const float* bq = (const float*)d_in[3];
  const float* wk = (const float*)d_in[4];
  const float* bk = (const float*)d_in[5];
  const float* wv = (const float*)d_in[6];
  const float* bv = (const float*)d_in[7];
  const float* wo = (const float*)d_in[8];
  const float* bo = (const float*)d_in[9];
  float* out = (float*)d_out;

  if (ws_size < (size_t)25165824 * 2) return;  // need ~48 MiB of scratch

  bf16* ws    = (bf16*)d_ws;
  bf16* xb    = ws;                     // [4096][1024]; reused as partials
  bf16* wqkvT = xb + 4194304;           // [3072][1024]
  bf16* woT   = wqkvT + 3145728;        // [1024][1024]
  bf16* qfp   = woT + 1048576;          // [4096][1024] flat
  bf16* kfrag = qfp + 4194304;          // KF fragment layout, 8 MiB
  bf16* vfrag = kfrag + 4194304;        // VF fragment layout, 8 MiB
  bf16* aop   = vfrag + 4194304;        // [4096][1024] flat

  // partial scratch (xb is dead after the QKV GEMM):
  bf16*  o2buf = xb;                         // 8qt*32bh*128*64 bf16 = 4 MiB
  float* mlbuf = (float*)(xb + 2097152);     // 8*32*2*2*128 f32 = 512 KiB

  prep_kernel<<<5120, 256, 0, stream>>>(x, xb, wq, wk, wv, wo, wqkvT);

  gemm_bt<0><<<32 * 24, 256, 0, stream>>>(xb, wqkvT, bq, bk, bv, qfp, kfrag,
                                          vfrag, nullptr, 24);
  attn_kernel<<<512, 256, 0, stream>>>(qfp, kfrag, vfrag, aop, o2buf, mlbuf);
  vmean_kernel<<<32, 256, 0, stream>>>(vfrag, aop);
  combine_kernel<<<256, 256, 0, stream>>>(o2buf, mlbuf, aop);
  gemm_bt<1><<<32 * 8, 256, 0, stream>>>(aop, woT, bo, nullptr, nullptr, nullptr,
                                         nullptr, nullptr, out, 8);
}